// Round 1
// baseline (293.743 us; speedup 1.0000x reference)
//
#include <hip/hip_runtime.h>
#include <hip/hip_bf16.h>

#define H_ 96
#define W_ 96
#define HW_ 9216
#define C_ 256
#define B_ 2
#define KO_ 27
#define EPS_ 1e-5f

typedef unsigned short ushort8 __attribute__((ext_vector_type(8)));
typedef short short8v __attribute__((ext_vector_type(8)));
typedef float float4v __attribute__((ext_vector_type(4)));

__device__ __forceinline__ float b2f(unsigned short u) {
    return __uint_as_float(((unsigned int)u) << 16);
}
__device__ __forceinline__ unsigned short f2b(float f) {
    __hip_bfloat16 h = __float2bfloat16(f);
    union { __hip_bfloat16 h; unsigned short u; } cv; cv.h = h; return cv.u;
}

// ---------------- kernel 1: weight repack + BN fold ----------------
// WP[o*2304 + k*256 + c] = bf16(w_conv[o*2304 + c*9 + k])
// A[o] = gamma*rsqrt(var+eps); B[o] = beta + (b_conv-mean)*A
__global__ __launch_bounds__(256) void prep_w_kernel(
    const float* __restrict__ w_conv, const float* __restrict__ b_conv,
    const float* __restrict__ gamma, const float* __restrict__ beta,
    const float* __restrict__ rmean, const float* __restrict__ rvar,
    float* __restrict__ AB, unsigned short* __restrict__ WP)
{
    int idx = blockIdx.x * 256 + threadIdx.x;
    if (blockIdx.x == 0) {
        int o = threadIdx.x;
        float sc = gamma[o] * rsqrtf(rvar[o] + EPS_);
        AB[o] = sc;
        AB[256 + o] = beta[o] + (b_conv[o] - rmean[o]) * sc;
    }
    int o = idx / 2304;
    int r = idx % 2304;
    int k = r / 256;
    int c = r % 256;
    WP[idx] = f2b(w_conv[o * 2304 + c * 9 + k]);
}

// ---------------- kernel 2: x NCHW f32 -> NHWC bf16 ----------------
__global__ __launch_bounds__(256) void xt_kernel(const float* __restrict__ x,
                                                 unsigned short* __restrict__ XT)
{
    __shared__ unsigned short ls[32][98];
    int b = blockIdx.x / H_;
    int h = blockIdx.x % H_;
    for (int c0 = 0; c0 < C_; c0 += 32) {
        __syncthreads();
        for (int e = threadIdx.x; e < 32 * W_; e += 256) {
            int ci = e / W_, w = e % W_;
            ls[ci][w] = f2b(x[((b * C_ + c0 + ci) * H_ + h) * W_ + w]);
        }
        __syncthreads();
        for (int e = threadIdx.x; e < 32 * W_; e += 256) {
            int w = e / 32, ci = e % 32;
            XT[((b * H_ + h) * W_ + w) * C_ + c0 + ci] = ls[ci][w];
        }
    }
}

// ---------------- kernel 3: offset conv (fp32), c-split 8 ----------------
// PART[((s*2+b)*27+ko)*9216 + pix] = partial conv sum over c in [s*32, s*32+32)
__global__ __launch_bounds__(256) void offconv_kernel(const float* __restrict__ x,
    const float* __restrict__ w_off, float* __restrict__ PART)
{
    __shared__ float xs[18 * 18];
    int tile = blockIdx.x;          // 0..35
    int b = blockIdx.y;
    int s = blockIdx.z;             // c-split
    int h0 = (tile / 6) * 16, w0 = (tile % 6) * 16;
    int tid = threadIdx.x;
    int py = tid / 16, px = tid % 16;
    float acc[27];
#pragma unroll
    for (int i = 0; i < 27; i++) acc[i] = 0.f;
    for (int ci = 0; ci < 32; ci++) {
        int c = s * 32 + ci;
        __syncthreads();
        for (int e = tid; e < 324; e += 256) {
            int r = e / 18, cl = e % 18;
            int gy = h0 + r - 1, gx = w0 + cl - 1;
            float v = 0.f;
            if (gy >= 0 && gy < H_ && gx >= 0 && gx < W_)
                v = x[((b * C_ + c) * H_ + gy) * W_ + gx];
            xs[e] = v;
        }
        __syncthreads();
        float xv[9];
#pragma unroll
        for (int a = 0; a < 3; a++)
#pragma unroll
            for (int bb = 0; bb < 3; bb++)
                xv[a * 3 + bb] = xs[(py + a) * 18 + px + bb];
        const float* wb = w_off + c * 9;   // uniform -> scalar loads
#pragma unroll
        for (int ko = 0; ko < 27; ko++) {
#pragma unroll
            for (int t = 0; t < 9; t++)
                acc[ko] = fmaf(xv[t], wb[ko * 2304 + t], acc[ko]);
        }
    }
    int pix = (h0 + py) * W_ + (w0 + px);
    int base = ((s * B_ + b) * KO_) * HW_ + pix;
#pragma unroll
    for (int ko = 0; ko < 27; ko++)
        PART[base + ko * HW_] = acc[ko];
}

// ---------------- kernel 4: reduce partials -> DY/DX/MASK ----------------
__global__ __launch_bounds__(256) void finalize_kernel(const float* __restrict__ PART,
    const float* __restrict__ b_off, float* __restrict__ DY, float* __restrict__ DX,
    float* __restrict__ MK)
{
    int idx = blockIdx.x * 256 + threadIdx.x;   // < 2*27*9216
    int b = idx / (KO_ * HW_);
    int r = idx % (KO_ * HW_);
    int ko = r / HW_;
    int pix = r % HW_;
    float v = b_off[ko];
#pragma unroll
    for (int s = 0; s < 8; s++)
        v += PART[((s * B_ + b) * KO_ + ko) * HW_ + pix];
    if (ko < 18) {
        int k = ko >> 1;
        float* dst = (ko & 1) ? DX : DY;
        dst[(b * 9 + k) * HW_ + pix] = v;
    } else {
        int k = ko - 18;
        MK[(b * 9 + k) * HW_ + pix] = 1.f / (1.f + expf(-v));
    }
}

// ---------------- kernel 5: deformable GEMM (bf16 MFMA) + BN/ReLU/residual ----
// Block: 128 o x 64 px, 4 waves (wave tile 64o x 32px), K = k*256+c, chunk = 32.
__global__ __launch_bounds__(256) void deform_kernel(
    const float* __restrict__ x, const unsigned short* __restrict__ XT,
    const unsigned short* __restrict__ WP,
    const float* __restrict__ DY, const float* __restrict__ DX,
    const float* __restrict__ MK, const float* __restrict__ AB,
    float* __restrict__ out)
{
    __shared__ __align__(16) unsigned short s_s[2][64][32];   // [px][k] bf16
    __shared__ __align__(16) unsigned short s_w[2][128][32];  // [o][k] bf16

    const int tid = threadIdx.x;
    const int b  = blockIdx.z;
    const int o0 = blockIdx.y * 128;
    const int ht = blockIdx.x / 6, wt = blockIdx.x % 6;
    const int h0 = ht * 4, w0 = wt * 16;   // pixel tile = 4 rows x 16 cols

    // s-fill mapping: 4 lanes per pixel (channel subgroups) -> line-friendly loads
    const int sub  = tid & 3;       // 8-channel subgroup
    const int pp_f = tid >> 2;      // pixel 0..63
    const int ph_f = h0 + (pp_f >> 4);
    const int pw_f = w0 + (pp_f & 15);
    const int pix_f = ph_f * W_ + pw_f;

    // w-fill mapping
    const int oo_w  = tid & 127;
    const int seg_w = tid >> 7;     // 0/1 -> 16 k's each

    // gemm mapping
    const int wave = tid >> 6;
    const int lane = tid & 63;
    const int quad = lane >> 4;
    const int l15  = lane & 15;
    const int wo = (wave >> 1) * 64;
    const int wp = (wave & 1) * 32;

    float4v acc[4][2];
#pragma unroll
    for (int i = 0; i < 4; i++)
#pragma unroll
        for (int j = 0; j < 2; j++)
            acc[i][j] = float4v{0.f, 0.f, 0.f, 0.f};

    // per-(k,pixel) bilinear params
    int a00, a01, a10, a11;
    float fw00, fw01, fw10, fw11;
    int kprm = -1;

    auto compute_params = [&](int k) {
        float dyv = DY[(b * 9 + k) * HW_ + pix_f];
        float dxv = DX[(b * 9 + k) * HW_ + pix_f];
        float m   = MK[(b * 9 + k) * HW_ + pix_f];
        float py = (float)(ph_f + (k / 3) - 1) + dyv;
        float px = (float)(pw_f + (k % 3) - 1) + dxv;
        float y0f = floorf(py), x0f = floorf(px);
        float ly = py - y0f, lx = px - x0f;
        int y0 = (int)y0f, x0 = (int)x0f;
        int y1 = y0 + 1, x1 = x0 + 1;
        bool vy0 = (y0 >= 0) && (y0 < H_);
        bool vy1 = (y1 >= 0) && (y1 < H_);
        bool vx0 = (x0 >= 0) && (x0 < W_);
        bool vx1 = (x1 >= 0) && (x1 < W_);
        fw00 = (vy0 && vx0) ? (1.f - ly) * (1.f - lx) * m : 0.f;
        fw01 = (vy0 && vx1) ? (1.f - ly) * lx * m : 0.f;
        fw10 = (vy1 && vx0) ? ly * (1.f - lx) * m : 0.f;
        fw11 = (vy1 && vx1) ? ly * lx * m : 0.f;
        int y0c = min(max(y0, 0), H_ - 1), y1c = min(max(y1, 0), H_ - 1);
        int x0c = min(max(x0, 0), W_ - 1), x1c = min(max(x1, 0), W_ - 1);
        a00 = ((b * H_ + y0c) * W_ + x0c) * C_;
        a01 = ((b * H_ + y0c) * W_ + x1c) * C_;
        a10 = ((b * H_ + y1c) * W_ + x0c) * C_;
        a11 = ((b * H_ + y1c) * W_ + x1c) * C_;
    };

    struct Regs { ushort8 v00, v01, v10, v11, wv0, wv1; };

    auto load_chunk = [&](int ch) {
        Regs rg;
        int k = ch >> 3;
        int cbase = (ch & 7) * 32;
        int coff = cbase + sub * 8;
        rg.v00 = *(const ushort8*)(XT + a00 + coff);
        rg.v01 = *(const ushort8*)(XT + a01 + coff);
        rg.v10 = *(const ushort8*)(XT + a10 + coff);
        rg.v11 = *(const ushort8*)(XT + a11 + coff);
        const unsigned short* wsrc =
            WP + (o0 + oo_w) * 2304 + k * 256 + cbase + seg_w * 16;
        rg.wv0 = *(const ushort8*)(wsrc);
        rg.wv1 = *(const ushort8*)(wsrc + 8);
        return rg;
    };

    auto store_chunk = [&](const Regs& rg, int bufw) {
        ushort8 sv;
#pragma unroll
        for (int j = 0; j < 8; j++) {
            float v = fw00 * b2f(rg.v00[j]) + fw01 * b2f(rg.v01[j])
                    + fw10 * b2f(rg.v10[j]) + fw11 * b2f(rg.v11[j]);
            sv[j] = f2b(v);
        }
        *(ushort8*)&s_s[bufw][pp_f][sub * 8] = sv;
        *(ushort8*)&s_w[bufw][oo_w][seg_w * 16]     = rg.wv0;
        *(ushort8*)&s_w[bufw][oo_w][seg_w * 16 + 8] = rg.wv1;
    };

    // prologue: chunk 0 into buffer 0
    compute_params(0); kprm = 0;
    {
        Regs rg = load_chunk(0);
        store_chunk(rg, 0);
    }
    __syncthreads();

    int buf = 0;
    for (int ch = 0; ch < 72; ch++) {
        Regs rgn;
        bool has_next = (ch + 1) < 72;
        if (has_next) {
            int kn = (ch + 1) >> 3;
            if (kn != kprm) { compute_params(kn); kprm = kn; }
            rgn = load_chunk(ch + 1);      // loads issued before MFMAs
        }
        // GEMM on current buffer
        short8v a_frag[4], b_frag[2];
#pragma unroll
        for (int mt = 0; mt < 4; mt++)
            a_frag[mt] = *(const short8v*)&s_w[buf][wo + mt * 16 + l15][quad * 8];
#pragma unroll
        for (int nt = 0; nt < 2; nt++)
            b_frag[nt] = *(const short8v*)&s_s[buf][wp + nt * 16 + l15][quad * 8];
#pragma unroll
        for (int mt = 0; mt < 4; mt++)
#pragma unroll
            for (int nt = 0; nt < 2; nt++)
                acc[mt][nt] = __builtin_amdgcn_mfma_f32_16x16x32_bf16(
                    a_frag[mt], b_frag[nt], acc[mt][nt], 0, 0, 0);
        if (has_next)
            store_chunk(rgn, buf ^ 1);
        __syncthreads();
        buf ^= 1;
    }

    // epilogue: fold BN+bias (A,B), relu, residual
    const float* Ao = AB;
    const float* Bo = AB + 256;
#pragma unroll
    for (int mt = 0; mt < 4; mt++) {
#pragma unroll
        for (int nt = 0; nt < 2; nt++) {
            int p = wp + nt * 16 + l15;
            int ph = h0 + (p >> 4), pw = w0 + (p & 15);
#pragma unroll
            for (int r = 0; r < 4; r++) {
                int o = o0 + wo + mt * 16 + quad * 4 + r;
                float v = acc[mt][nt][r] * Ao[o] + Bo[o];
                v = fmaxf(v, 0.f);
                int gi = ((b * C_ + o) * H_ + ph) * W_ + pw;
                out[gi] = x[gi] + v;
            }
        }
    }
}

extern "C" void kernel_launch(void* const* d_in, const int* in_sizes, int n_in,
                              void* d_out, int out_size, void* d_ws, size_t ws_size,
                              hipStream_t stream)
{
    (void)in_sizes; (void)n_in; (void)out_size; (void)ws_size;
    const float* x      = (const float*)d_in[0];
    const float* w_off  = (const float*)d_in[1];
    const float* b_off  = (const float*)d_in[2];
    const float* w_conv = (const float*)d_in[3];
    const float* b_conv = (const float*)d_in[4];
    const float* gamma  = (const float*)d_in[5];
    const float* beta   = (const float*)d_in[6];
    const float* rmean  = (const float*)d_in[7];
    const float* rvar   = (const float*)d_in[8];
    float* out = (float*)d_out;

    float* ws = (float*)d_ws;
    float* DY   = ws;                          // 2*9*9216
    float* DX   = DY + 2 * 9 * HW_;
    float* MK   = DX + 2 * 9 * HW_;
    float* PART = MK + 2 * 9 * HW_;            // 8*2*27*9216
    float* AB   = PART + 8 * 2 * 27 * HW_;     // 512
    unsigned short* WP = (unsigned short*)(AB + 512);   // 2304*256 bf16
    unsigned short* XT = WP + 2304 * 256;               // 2*96*96*256 bf16

    prep_w_kernel<<<2304, 256, 0, stream>>>(w_conv, b_conv, gamma, beta, rmean, rvar, AB, WP);
    xt_kernel<<<192, 256, 0, stream>>>(x, XT);
    offconv_kernel<<<dim3(36, 2, 8), 256, 0, stream>>>(x, w_off, PART);
    finalize_kernel<<<1944, 256, 0, stream>>>(PART, b_off, DY, DX, MK);
    deform_kernel<<<dim3(144, 2, 2), 256, 0, stream>>>(x, XT, WP, DY, DX, MK, AB, out);
}